// Round 6
// baseline (447.441 us; speedup 1.0000x reference)
//
#include <hip/hip_runtime.h>
#include <stdint.h>

typedef __attribute__((ext_vector_type(4))) int i32x4;

// BinaryConv: out = sign(conv2d(sign(x), sign(w), pad=1) + bias)
// x: [32,256,56,56] f32, w: [256,256,3,3] f32, bias: [256] f32, out: [32,256,56,56] f32
// i8 MFMA implicit GEMM: M=100352 pixels, N=256 out-ch, K=2304 (9 taps x 256 ch).
// Padded NHWC i8 sign tensor (border=0) makes zero-padding exact; i32 accum is exact.

#define NB 32
#define CC 256
#define HH 56
#define WW 56
#define OO 256
#define PH 58
#define PW 58
#define SS (HH*WW)      // 3136
#define KTOT 2304
#define BROW 2320       // LDS row pitch for B (2304 + 16 pad -> bank shift 4/row)

// ============================ MFMA path =============================================

// xs: [n][ph][pw][c] i8, border rows/cols = 0
__global__ __launch_bounds__(256) void pack_xs_kernel(const float* __restrict__ x,
                                                      int8_t* __restrict__ xs) {
    int c  = threadIdx.x;          // channel
    int ph = blockIdx.x;           // 0..57 padded row
    int n  = blockIdx.y;
    int8_t* dst = xs + (((size_t)n * PH + ph) * PW) * 256 + c;
    if (ph == 0 || ph == PH - 1) {
        for (int pw = 0; pw < PW; ++pw) dst[(size_t)pw * 256] = 0;
        return;
    }
    int h = ph - 1;
    const float* src = x + ((size_t)(n * CC + c) * HH + h) * WW;
    dst[0] = 0;
    dst[(size_t)(PW - 1) * 256] = 0;
    for (int w = 0; w < WW; ++w) {
        float v = src[w];                       // per-thread sequential 224 B
        int8_t s = (v > 0.f) ? 1 : ((v < 0.f) ? -1 : 0);
        dst[(size_t)(w + 1) * 256] = s;         // 256B coalesced across threads
    }
}

// wsB: [o][t][c] i8 (t = kh*3+kw)
__global__ __launch_bounds__(256) void pack_wsB_kernel(const float* __restrict__ wgt,
                                                       int8_t* __restrict__ wsB) {
    int c = threadIdx.x;
    int o = blockIdx.x;
    const float* src = wgt + ((size_t)o * CC + c) * 9;
#pragma unroll
    for (int t = 0; t < 9; ++t) {
        float v = src[t];
        int8_t s = (v > 0.f) ? 1 : ((v < 0.f) ? -1 : 0);
        wsB[(size_t)o * KTOT + t * 256 + c] = s;
    }
}

// Block: 256 thr = 4 waves. M_blk = 256 pixels (wave: 4 subtiles of 16), N_blk = 16.
// B o-slice (16 x 2304 i8) staged once in LDS with padded rows; no barriers in K-loop.
// A-frag: lane holds pixel row (l&15), k-bytes (l>>4)*16..+15 (contiguous-16 pattern,
// matching the ref-checked gfx950 16x16xK fragment layout). C/D: col=l&15 (o),
// row=(l>>4)*4+reg (pixel). Grid: x = M-block (392), y = N-block (16); 392%8==0 so all
// 16 same-window N-blocks land on one XCD under round-robin -> A is L2-shared.
__global__ __launch_bounds__(256, 4) void bconv_mfma_kernel(const int8_t* __restrict__ xs,
                                                            const int8_t* __restrict__ wsB,
                                                            const float* __restrict__ bias,
                                                            float* __restrict__ out) {
    __shared__ __align__(16) int8_t Bsm[16 * BROW];   // 37120 B
    int tid = threadIdx.x;
    int l   = tid & 63;
    int wid = tid >> 6;
    int o0  = blockIdx.y * 16;

    // stage B: thread i copies 144 B of o-row (i>>4), segment (i&15)
    {
        int ol = tid >> 4, seg = tid & 15;
        const int8_t* src = wsB + (size_t)(o0 + ol) * KTOT + seg * 144;
        int8_t* dst = Bsm + ol * BROW + seg * 144;
#pragma unroll
        for (int j = 0; j < 9; ++j)
            *(i32x4*)(dst + j * 16) = *(const i32x4*)(src + j * 16);
    }
    __syncthreads();

    const int lg = l >> 4;     // k-group 0..3
    const int lr = l & 15;     // row (A) / col (B,C)

    const int g0 = blockIdx.x * 256 + wid * 64;   // wave's first pixel
    uint32_t apix[4];
#pragma unroll
    for (int s = 0; s < 4; ++s) {
        int p  = g0 + s * 16 + lr;                // pixel (16 | 3136 -> same n per subtile)
        int n  = p / SS;
        int sp = p - n * SS;
        int h  = sp / WW;
        int w  = sp - h * WW;
        apix[s] = (uint32_t)(((n * PH + h) * PW + w) * 256 + lg * 16);
    }
    const int bbase = lr * BROW + lg * 16;

    i32x4 acc0 = {0,0,0,0}, acc1 = {0,0,0,0}, acc2 = {0,0,0,0}, acc3 = {0,0,0,0};

#pragma unroll
    for (int cg = 0; cg < 4; ++cg) {              // channel 64-group
#pragma unroll
        for (int t = 0; t < 9; ++t) {             // tap (t-inner: L1 reuse of window)
            const int r = t / 3, kk = t - r * 3;
            const int aoff = (r * PW + kk) * 256 + cg * 64;
            i32x4 bv = *(const i32x4*)(Bsm + bbase + t * 256 + cg * 64);
            i32x4 a0 = *(const i32x4*)(xs + apix[0] + aoff);
            i32x4 a1 = *(const i32x4*)(xs + apix[1] + aoff);
            i32x4 a2 = *(const i32x4*)(xs + apix[2] + aoff);
            i32x4 a3 = *(const i32x4*)(xs + apix[3] + aoff);
            asm volatile("v_mfma_i32_16x16x64_i8 %0, %1, %2, %0" : "+v"(acc0) : "v"(a0), "v"(bv));
            asm volatile("v_mfma_i32_16x16x64_i8 %0, %1, %2, %0" : "+v"(acc1) : "v"(a1), "v"(bv));
            asm volatile("v_mfma_i32_16x16x64_i8 %0, %1, %2, %0" : "+v"(acc2) : "v"(a2), "v"(bv));
            asm volatile("v_mfma_i32_16x16x64_i8 %0, %1, %2, %0" : "+v"(acc3) : "v"(a3), "v"(bv));
        }
    }
    asm volatile("s_nop 7\n\ts_nop 7\n\ts_nop 7" ::);   // MFMA -> VALU read hazard guard

    float bo = bias[o0 + lr];
#pragma unroll
    for (int s = 0; s < 4; ++s) {
        i32x4 a = (s == 0) ? acc0 : ((s == 1) ? acc1 : ((s == 2) ? acc2 : acc3));
        int pst = g0 + s * 16 + lg * 4;           // first of this lane's 4 output pixels
        int n   = pst / SS;
        int sp  = pst - n * SS;
        float v0 = (float)a.x + bo;
        float v1 = (float)a.y + bo;
        float v2 = (float)a.z + bo;
        float v3 = (float)a.w + bo;
        float4 r4;
        r4.x = (v0 > 0.f) ? 1.f : ((v0 < 0.f) ? -1.f : 0.f);
        r4.y = (v1 > 0.f) ? 1.f : ((v1 < 0.f) ? -1.f : 0.f);
        r4.z = (v2 > 0.f) ? 1.f : ((v2 < 0.f) ? -1.f : 0.f);
        r4.w = (v3 > 0.f) ? 1.f : ((v3 < 0.f) ? -1.f : 0.f);
        *(float4*)(out + ((size_t)(n * OO + o0 + lr)) * SS + sp) = r4;
    }
}

// ============================ fallback popcount path (R4, 163 us) ===================

#define SPAD (PH*PW)
#define CWN  4

__global__ __launch_bounds__(256) void pack_x_kernel(const float* __restrict__ x,
                                                     uint64_t* __restrict__ px) {
    int tid = threadIdx.x;
    int sp  = blockIdx.x * 256 + tid;
    int cw  = blockIdx.y;
    int n   = blockIdx.z;
    if (sp >= SPAD) return;
    int ph = sp / PW, pw_ = sp % PW;
    uint64_t* dst = px + (((size_t)n * CWN + cw) * SPAD + sp);
    if (ph == 0 || ph == PH - 1 || pw_ == 0 || pw_ == PW - 1) { *dst = 0ull; return; }
    int h = ph - 1, w = pw_ - 1;
    const float* src = x + ((size_t)(n * CC + cw * 64)) * SS + (h * WW + w);
    uint32_t lo = 0u, hi = 0u;
#pragma unroll
    for (int j = 0; j < 32; ++j) { float v = src[(size_t)j * SS];        lo |= (v > 0.0f ? 1u : 0u) << j; }
#pragma unroll
    for (int j = 0; j < 32; ++j) { float v = src[(size_t)(j + 32) * SS]; hi |= (v > 0.0f ? 1u : 0u) << j; }
    *dst = ((uint64_t)hi << 32) | (uint64_t)lo;
}

__global__ __launch_bounds__(256) void pack_w_kernel(const float* __restrict__ wgt,
                                                     uint64_t* __restrict__ pwb) {
    int lane = threadIdx.x & 63;
    int wave = threadIdx.x >> 6;
    int wi   = blockIdx.x * 4 + wave;
    if (wi >= OO * 9 * CWN) return;
    int o = wi / 36, rem = wi % 36, t = rem >> 2, cw = rem & 3;
    int c = cw * 64 + lane;
    float v = wgt[(size_t)(o * CC + c) * 9 + t];
    uint64_t m = __ballot(v > 0.0f);
    if (lane == 0) pwb[wi] = m;
}

__global__ __launch_bounds__(256) void build_k_kernel(const uint64_t* __restrict__ pwb,
                                                      int* __restrict__ ktab) {
    int o = threadIdx.x;
    int pops[9];
#pragma unroll
    for (int t = 0; t < 9; ++t) {
        int p = 0;
#pragma unroll
        for (int cw = 0; cw < 4; ++cw) p += __popcll(pwb[o * 36 + t * 4 + cw]);
        pops[t] = p;
    }
#pragma unroll
    for (int cls = 0; cls < 9; ++cls) {
        int vf = cls / 3, hf = cls % 3;
        int K = 9 * CC;
#pragma unroll
        for (int t = 0; t < 9; ++t) {
            int r = t / 3, k = t % 3;
            bool inv = (vf == 1 && r == 0) || (vf == 2 && r == 2) ||
                       (hf == 1 && k == 0) || (hf == 2 && k == 2);
            if (inv) K -= (CC - 2 * pops[t]);
        }
        ktab[cls * OO + o] = K;
    }
}

__global__ __launch_bounds__(256, 4) void bconv_kernel(const uint64_t* __restrict__ px,
                                                       const uint64_t* __restrict__ pwb,
                                                       const int* __restrict__ ktab,
                                                       const float* __restrict__ bias,
                                                       float* __restrict__ out) {
    int g = blockIdx.x * 256 + threadIdx.x;
    int n = g / SS;
    int sid = g - n * SS;
    int obase = blockIdx.y * 32;
    int h = sid / WW, w = sid - h * WW;
    int vf = (h == 0) ? 1 : ((h == HH - 1) ? 2 : 0);
    int hf = (w == 0) ? 1 : ((w == WW - 1) ? 2 : 0);
    const int* krow = ktab + (vf * 3 + hf) * OO + obase;
    const uint64_t* pb = px + (size_t)n * CWN * SPAD + h * PW + w;
    const uint32_t* wb = (const uint32_t*)pwb + (size_t)obase * 72;
    uint32_t acc[32];
#pragma unroll
    for (int i = 0; i < 32; ++i) acc[i] = 0u;
#pragma unroll 1
    for (int r = 0; r < 3; ++r) {
#pragma unroll 1
        for (int k = 0; k < 3; ++k) {
            int off = r * PW + k;
            uint64_t q0 = pb[off];
            uint64_t q1 = pb[SPAD + off];
            uint64_t q2 = pb[2 * SPAD + off];
            uint64_t q3 = pb[3 * SPAD + off];
            uint32_t pa0 = (uint32_t)q0, pa1 = (uint32_t)(q0 >> 32);
            uint32_t pa2 = (uint32_t)q1, pa3 = (uint32_t)(q1 >> 32);
            uint32_t pa4 = (uint32_t)q2, pa5 = (uint32_t)(q2 >> 32);
            uint32_t pa6 = (uint32_t)q3, pa7 = (uint32_t)(q3 >> 32);
            int t8 = (r * 3 + k) * 8;
#pragma unroll
            for (int oi = 0; oi < 32; ++oi) {
                const uint32_t* wv = wb + oi * 72 + t8;
                uint32_t a = acc[oi];
                a = __popc(pa0 ^ wv[0]) + a;
                a = __popc(pa1 ^ wv[1]) + a;
                a = __popc(pa2 ^ wv[2]) + a;
                a = __popc(pa3 ^ wv[3]) + a;
                a = __popc(pa4 ^ wv[4]) + a;
                a = __popc(pa5 ^ wv[5]) + a;
                a = __popc(pa6 ^ wv[6]) + a;
                a = __popc(pa7 ^ wv[7]) + a;
                acc[oi] = a;
            }
        }
    }
    float* orow = out + ((size_t)(n * OO + obase)) * SS + sid;
#pragma unroll
    for (int oi = 0; oi < 32; ++oi) {
        int s = krow[oi] - 2 * (int)acc[oi];
        float v = (float)s + bias[obase + oi];
        float res = (v > 0.0f) ? 1.0f : ((v < 0.0f) ? -1.0f : 0.0f);
        orow[(size_t)oi * SS] = res;
    }
}

// ============================ launch ================================================

extern "C" void kernel_launch(void* const* d_in, const int* in_sizes, int n_in,
                              void* d_out, int out_size, void* d_ws, size_t ws_size,
                              hipStream_t stream) {
    const float* x    = (const float*)d_in[0];
    const float* wgt  = (const float*)d_in[1];
    const float* bias = (const float*)d_in[2];
    float* out = (float*)d_out;

    const size_t wsB_bytes = (size_t)OO * KTOT;                 // 589,824
    const size_t xs_bytes  = (size_t)NB * PH * PW * 256;        // 27,557,888
    if (ws_size >= wsB_bytes + xs_bytes) {
        int8_t* wsB = (int8_t*)d_ws;
        int8_t* xs  = (int8_t*)d_ws + wsB_bytes;
        pack_xs_kernel<<<dim3(PH, NB), 256, 0, stream>>>(x, xs);
        pack_wsB_kernel<<<dim3(OO), 256, 0, stream>>>(wgt, wsB);
        bconv_mfma_kernel<<<dim3(NB * SS / 256, OO / 16), 256, 0, stream>>>(xs, wsB, bias, out);
    } else {
        // fallback: proven popcount path (R4)
        size_t px_bytes = (size_t)NB * CWN * SPAD * 8;
        size_t pw_off   = px_bytes;
        size_t pw_bytes = (size_t)OO * 9 * CWN * 8;
        size_t k_off    = pw_off + pw_bytes;
        uint64_t* px  = (uint64_t*)d_ws;
        uint64_t* pwb = (uint64_t*)((char*)d_ws + pw_off);
        int*      kt  = (int*)((char*)d_ws + k_off);
        dim3 gpx((SPAD + 255) / 256, CWN, NB);
        pack_x_kernel<<<gpx, 256, 0, stream>>>(x, px);
        int nwords = OO * 9 * CWN;
        pack_w_kernel<<<dim3((nwords + 3) / 4), 256, 0, stream>>>(wgt, pwb);
        build_k_kernel<<<dim3(1), 256, 0, stream>>>(pwb, kt);
        dim3 gcv(NB * SS / 256, OO / 32, 1);
        bconv_kernel<<<gcv, 256, 0, stream>>>(px, pwb, kt, bias, out);
    }
}

// Round 8
// 350.812 us; speedup vs baseline: 1.2754x; 1.2754x over previous
//
#include <hip/hip_runtime.h>
#include <stdint.h>

typedef __attribute__((ext_vector_type(4))) int i32x4;

// BinaryConv: out = sign(conv2d(sign(x), sign(w), pad=1) + bias)
// x: [32,256,56,56] f32, w: [256,256,3,3] f32, bias: [256] f32, out: [32,256,56,56] f32
// i8 MFMA implicit GEMM: M=100352 pixels, N=256 out-ch, K=2304 (9 taps x 256 ch).
// Padded NHWC i8 sign tensor (border=0) makes zero-padding exact; i32 accum is exact.

#define NB 32
#define CC 256
#define HH 56
#define WW 56
#define OO 256
#define PH 58
#define PW 58
#define SS (HH*WW)      // 3136
#define KTOT 2304

// ============================ MFMA path =============================================

// xs: [n][ph][pw][c] i8, border rows/cols = 0
__global__ __launch_bounds__(256) void pack_xs_kernel(const float* __restrict__ x,
                                                      int8_t* __restrict__ xs) {
    int c  = threadIdx.x;          // channel
    int ph = blockIdx.x;           // 0..57 padded row
    int n  = blockIdx.y;
    int8_t* dst = xs + (((size_t)n * PH + ph) * PW) * 256 + c;
    if (ph == 0 || ph == PH - 1) {
        for (int pw = 0; pw < PW; ++pw) dst[(size_t)pw * 256] = 0;
        return;
    }
    int h = ph - 1;
    const float* src = x + ((size_t)(n * CC + c) * HH + h) * WW;
    dst[0] = 0;
    dst[(size_t)(PW - 1) * 256] = 0;
    for (int w = 0; w < WW; ++w) {
        float v = src[w];
        int8_t s = (v > 0.f) ? 1 : ((v < 0.f) ? -1 : 0);
        dst[(size_t)(w + 1) * 256] = s;         // 256B coalesced across threads
    }
}

// wsB: [o][t][c] i8 (t = kh*3+kw)
__global__ __launch_bounds__(256) void pack_wsB_kernel(const float* __restrict__ wgt,
                                                       int8_t* __restrict__ wsB) {
    int c = threadIdx.x;
    int o = blockIdx.x;
    const float* src = wgt + ((size_t)o * CC + c) * 9;
#pragma unroll
    for (int t = 0; t < 9; ++t) {
        float v = src[t];
        int8_t s = (v > 0.f) ? 1 : ((v < 0.f) ? -1 : 0);
        wsB[(size_t)o * KTOT + t * 256 + c] = s;
    }
}

// Block = 256 thr = 4 waves; tile BM=128 pixels x BN=64 out-ch. Wave (wm,wn) owns
// 64 pixels x 32 ch = 4 M-subtiles x 2 N-subtiles of 16x16x64 i8 MFMA (8 MFMA : 6 loads
// per K-step). No LDS: A and B frags stream from global (B is 590 KB, L2-hot; A made
// XCD-local by the block swizzle below). Explicit ping-pong prefetch, builtin MFMA so
// the scheduler overlaps loads with the matrix pipe.
// Block swizzle: flat b -> xcd=b&7 (HW round-robin), per-XCD index ix=b>>3;
// m = xcd + 8*(ix>>2), nb = ix&3  => all 4 N-blocks of an M-tile run consecutively on
// ONE XCD (A tile read once into that XCD's L2); bijective for 3136 blocks.
#define LOADK(STEP, A, B) do {                                              \
    const int _cg = (STEP) / 9, _t = (STEP) % 9;                            \
    const int _r = _t / 3, _k = _t % 3;                                     \
    const uint32_t _ao = (uint32_t)((_r * PW + _k) * 256 + _cg * 64);       \
    const uint32_t _bo = (uint32_t)(_t * 256 + _cg * 64);                   \
    A[0] = *(const i32x4*)(xs + apix[0] + _ao);                             \
    A[1] = *(const i32x4*)(xs + apix[1] + _ao);                             \
    A[2] = *(const i32x4*)(xs + apix[2] + _ao);                             \
    A[3] = *(const i32x4*)(xs + apix[3] + _ao);                             \
    B[0] = *(const i32x4*)(wsB + bofs[0] + _bo);                            \
    B[1] = *(const i32x4*)(wsB + bofs[1] + _bo);                            \
} while (0)

#define MFMA8(A, B) do {                                                    \
    _Pragma("unroll")                                                       \
    for (int _s = 0; _s < 4; ++_s) {                                        \
        acc[_s][0] = __builtin_amdgcn_mfma_i32_16x16x64_i8(A[_s], B[0], acc[_s][0], 0, 0, 0); \
        acc[_s][1] = __builtin_amdgcn_mfma_i32_16x16x64_i8(A[_s], B[1], acc[_s][1], 0, 0, 0); \
    }                                                                       \
} while (0)

__global__ __launch_bounds__(256, 4) void bconv_mfma_kernel(const int8_t* __restrict__ xs,
                                                            const int8_t* __restrict__ wsB,
                                                            const float* __restrict__ bias,
                                                            float* __restrict__ out) {
    int b   = blockIdx.x;                 // 0..3135
    int xcd = b & 7;
    int ix  = b >> 3;                     // 0..391
    int m   = xcd + 8 * (ix >> 2);        // 0..783 M-tile
    int nb  = ix & 3;                     // 0..3   N-tile

    int tid = threadIdx.x;
    int l   = tid & 63;
    int wid = tid >> 6;
    int lg  = l >> 4;                     // k-group 0..3
    int lr  = l & 15;                     // row (A) / col (B,C)
    int wm  = wid & 1, wn = wid >> 1;

    const int M0 = m * 128 + wm * 64;     // wave's first pixel
    const int O0 = nb * 64 + wn * 32;     // wave's first out-ch

    // A pixel byte-offsets for the 4 M-subtiles (per-lane; 16 | SS so subtile = one n)
    uint32_t apix[4];
#pragma unroll
    for (int s = 0; s < 4; ++s) {
        int p  = M0 + s * 16 + lr;
        int n  = p / SS;
        int sp = p - n * SS;
        int h  = sp / WW;
        int w  = sp - h * WW;
        apix[s] = (uint32_t)(((n * PH + h) * PW + w) * 256 + lg * 16);
    }
    // B byte-offsets for the 2 N-subtiles
    uint32_t bofs[2];
#pragma unroll
    for (int u = 0; u < 2; ++u)
        bofs[u] = (uint32_t)((O0 + u * 16 + lr) * KTOT + lg * 16);

    i32x4 acc[4][2];
#pragma unroll
    for (int s = 0; s < 4; ++s)
#pragma unroll
        for (int u = 0; u < 2; ++u)
            acc[s][u] = (i32x4){0, 0, 0, 0};

    i32x4 A0[4], B0[2], A1[4], B1[2];
    LOADK(0, A0, B0);
#pragma unroll
    for (int st = 0; st < 36; st += 2) {
        if (st + 1 < 36) LOADK(st + 1, A1, B1);
        MFMA8(A0, B0);
        if (st + 2 < 36) LOADK(st + 2, A0, B0);
        MFMA8(A1, B1);
    }

    float bo[2];
#pragma unroll
    for (int u = 0; u < 2; ++u) bo[u] = bias[O0 + u * 16 + lr];

    // C/D: col = lr (out-ch), row = lg*4 + reg (pixel) -- bit-exact mapping from R6
#pragma unroll
    for (int s = 0; s < 4; ++s) {
#pragma unroll
        for (int u = 0; u < 2; ++u) {
            i32x4 a = acc[s][u];
            int pst = M0 + s * 16 + lg * 4;          // lane's 4 consecutive pixels
            int n   = pst / SS;
            int sp  = pst - n * SS;
            int o   = O0 + u * 16 + lr;
            float v0 = (float)a.x + bo[u];
            float v1 = (float)a.y + bo[u];
            float v2 = (float)a.z + bo[u];
            float v3 = (float)a.w + bo[u];
            float4 r4;
            r4.x = (v0 > 0.f) ? 1.f : ((v0 < 0.f) ? -1.f : 0.f);
            r4.y = (v1 > 0.f) ? 1.f : ((v1 < 0.f) ? -1.f : 0.f);
            r4.z = (v2 > 0.f) ? 1.f : ((v2 < 0.f) ? -1.f : 0.f);
            r4.w = (v3 > 0.f) ? 1.f : ((v3 < 0.f) ? -1.f : 0.f);
            *(float4*)(out + ((size_t)(n * OO + o)) * SS + sp) = r4;
        }
    }
}

// ============================ fallback popcount path (R4, 163 us) ===================

#define SPAD (PH*PW)
#define CWN  4

__global__ __launch_bounds__(256) void pack_x_kernel(const float* __restrict__ x,
                                                     uint64_t* __restrict__ px) {
    int tid = threadIdx.x;
    int sp  = blockIdx.x * 256 + tid;
    int cw  = blockIdx.y;
    int n   = blockIdx.z;
    if (sp >= SPAD) return;
    int ph = sp / PW, pw_ = sp % PW;
    uint64_t* dst = px + (((size_t)n * CWN + cw) * SPAD + sp);
    if (ph == 0 || ph == PH - 1 || pw_ == 0 || pw_ == PW - 1) { *dst = 0ull; return; }
    int h = ph - 1, w = pw_ - 1;
    const float* src = x + ((size_t)(n * CC + cw * 64)) * SS + (h * WW + w);
    uint32_t lo = 0u, hi = 0u;
#pragma unroll
    for (int j = 0; j < 32; ++j) { float v = src[(size_t)j * SS];        lo |= (v > 0.0f ? 1u : 0u) << j; }
#pragma unroll
    for (int j = 0; j < 32; ++j) { float v = src[(size_t)(j + 32) * SS]; hi |= (v > 0.0f ? 1u : 0u) << j; }
    *dst = ((uint64_t)hi << 32) | (uint64_t)lo;
}

__global__ __launch_bounds__(256) void pack_w_kernel(const float* __restrict__ wgt,
                                                     uint64_t* __restrict__ pwb) {
    int lane = threadIdx.x & 63;
    int wave = threadIdx.x >> 6;
    int wi   = blockIdx.x * 4 + wave;
    if (wi >= OO * 9 * CWN) return;
    int o = wi / 36, rem = wi % 36, t = rem >> 2, cw = rem & 3;
    int c = cw * 64 + lane;
    float v = wgt[(size_t)(o * CC + c) * 9 + t];
    uint64_t m = __ballot(v > 0.0f);
    if (lane == 0) pwb[wi] = m;
}

__global__ __launch_bounds__(256) void build_k_kernel(const uint64_t* __restrict__ pwb,
                                                      int* __restrict__ ktab) {
    int o = threadIdx.x;
    int pops[9];
#pragma unroll
    for (int t = 0; t < 9; ++t) {
        int p = 0;
#pragma unroll
        for (int cw = 0; cw < 4; ++cw) p += __popcll(pwb[o * 36 + t * 4 + cw]);
        pops[t] = p;
    }
#pragma unroll
    for (int cls = 0; cls < 9; ++cls) {
        int vf = cls / 3, hf = cls % 3;
        int K = 9 * CC;
#pragma unroll
        for (int t = 0; t < 9; ++t) {
            int r = t / 3, k = t % 3;
            bool inv = (vf == 1 && r == 0) || (vf == 2 && r == 2) ||
                       (hf == 1 && k == 0) || (hf == 2 && k == 2);
            if (inv) K -= (CC - 2 * pops[t]);
        }
        ktab[cls * OO + o] = K;
    }
}

__global__ __launch_bounds__(256, 4) void bconv_kernel(const uint64_t* __restrict__ px,
                                                       const uint64_t* __restrict__ pwb,
                                                       const int* __restrict__ ktab,
                                                       const float* __restrict__ bias,
                                                       float* __restrict__ out) {
    int g = blockIdx.x * 256 + threadIdx.x;
    int n = g / SS;
    int sid = g - n * SS;
    int obase = blockIdx.y * 32;
    int h = sid / WW, w = sid - h * WW;
    int vf = (h == 0) ? 1 : ((h == HH - 1) ? 2 : 0);
    int hf = (w == 0) ? 1 : ((w == WW - 1) ? 2 : 0);
    const int* krow = ktab + (vf * 3 + hf) * OO + obase;
    const uint64_t* pb = px + (size_t)n * CWN * SPAD + h * PW + w;
    const uint32_t* wb = (const uint32_t*)pwb + (size_t)obase * 72;
    uint32_t acc[32];
#pragma unroll
    for (int i = 0; i < 32; ++i) acc[i] = 0u;
#pragma unroll 1
    for (int r = 0; r < 3; ++r) {
#pragma unroll 1
        for (int k = 0; k < 3; ++k) {
            int off = r * PW + k;
            uint64_t q0 = pb[off];
            uint64_t q1 = pb[SPAD + off];
            uint64_t q2 = pb[2 * SPAD + off];
            uint64_t q3 = pb[3 * SPAD + off];
            uint32_t pa0 = (uint32_t)q0, pa1 = (uint32_t)(q0 >> 32);
            uint32_t pa2 = (uint32_t)q1, pa3 = (uint32_t)(q1 >> 32);
            uint32_t pa4 = (uint32_t)q2, pa5 = (uint32_t)(q2 >> 32);
            uint32_t pa6 = (uint32_t)q3, pa7 = (uint32_t)(q3 >> 32);
            int t8 = (r * 3 + k) * 8;
#pragma unroll
            for (int oi = 0; oi < 32; ++oi) {
                const uint32_t* wv = wb + oi * 72 + t8;
                uint32_t a = acc[oi];
                a = __popc(pa0 ^ wv[0]) + a;
                a = __popc(pa1 ^ wv[1]) + a;
                a = __popc(pa2 ^ wv[2]) + a;
                a = __popc(pa3 ^ wv[3]) + a;
                a = __popc(pa4 ^ wv[4]) + a;
                a = __popc(pa5 ^ wv[5]) + a;
                a = __popc(pa6 ^ wv[6]) + a;
                a = __popc(pa7 ^ wv[7]) + a;
                acc[oi] = a;
            }
        }
    }
    float* orow = out + ((size_t)(n * OO + obase)) * SS + sid;
#pragma unroll
    for (int oi = 0; oi < 32; ++oi) {
        int s = krow[oi] - 2 * (int)acc[oi];
        float v = (float)s + bias[obase + oi];
        float res = (v > 0.0f) ? 1.0f : ((v < 0.0f) ? -1.0f : 0.0f);
        orow[(size_t)oi * SS] = res;
    }
}

// ============================ launch ================================================

extern "C" void kernel_launch(void* const* d_in, const int* in_sizes, int n_in,
                              void* d_out, int out_size, void* d_ws, size_t ws_size,
                              hipStream_t stream) {
    const float* x    = (const float*)d_in[0];
    const float* wgt  = (const float*)d_in[1];
    const float* bias = (const float*)d_in[2];
    float* out = (float*)d_out;

    const size_t wsB_bytes = (size_t)OO * KTOT;                 // 589,824
    const size_t xs_bytes  = (size_t)NB * PH * PW * 256;        // 27,557,888
    if (ws_size >= wsB_bytes + xs_bytes) {
        int8_t* wsB = (int8_t*)d_ws;
        int8_t* xs  = (int8_t*)d_ws + wsB_bytes;
        pack_xs_kernel<<<dim3(PH, NB), 256, 0, stream>>>(x, xs);
        pack_wsB_kernel<<<dim3(OO), 256, 0, stream>>>(wgt, wsB);
        // grid = (M/128) * (N/64) = 784 * 4 = 3136 blocks (1D, swizzled in-kernel).
        // R7 BUG was here: left-to-right int arithmetic gave 784. Fixed: explicit.
        const int n_blocks = (NB * SS / 128) * (OO / 64);       // 3136
        bconv_mfma_kernel<<<dim3(n_blocks), 256, 0, stream>>>(xs, wsB, bias, out);
    } else {
        // fallback: proven popcount path (R4)
        size_t px_bytes = (size_t)NB * CWN * SPAD * 8;
        size_t pw_off   = px_bytes;
        size_t pw_bytes = (size_t)OO * 9 * CWN * 8;
        size_t k_off    = pw_off + pw_bytes;
        uint64_t* px  = (uint64_t*)d_ws;
        uint64_t* pwb = (uint64_t*)((char*)d_ws + pw_off);
        int*      kt  = (int*)((char*)d_ws + k_off);
        dim3 gpx((SPAD + 255) / 256, CWN, NB);
        pack_x_kernel<<<gpx, 256, 0, stream>>>(x, px);
        int nwords = OO * 9 * CWN;
        pack_w_kernel<<<dim3((nwords + 3) / 4), 256, 0, stream>>>(wgt, pwb);
        build_k_kernel<<<dim3(1), 256, 0, stream>>>(pwb, kt);
        dim3 gcv(NB * SS / 256, OO / 32, 1);
        bconv_kernel<<<gcv, 256, 0, stream>>>(px, pwb, kt, bias, out);
    }
}

// Round 9
// 129.283 us; speedup vs baseline: 3.4609x; 2.7135x over previous
//
#include <hip/hip_runtime.h>
#include <stdint.h>

typedef __attribute__((ext_vector_type(4))) int i32x4;

// BinaryConv: out = sign(conv2d(sign(x), sign(w), pad=1) + bias)
// i8 MFMA implicit GEMM, m97-style 2-phase LDS double-buffer schedule.
// M=100352 pixels, N=256 out-ch, K=2304 (9 taps x 256 ch). Exact i32 arithmetic.

#define NB 32
#define CC 256
#define HH 56
#define WW 56
#define OO 256
#define PH 58
#define PW 58
#define SS (HH*WW)      // 3136
#define KTOT 2304

// ---- async global->LDS, 16B per lane; dest = wave-uniform base + lane*16 -----------
__device__ __forceinline__ void gload16(const void* g, void* l) {
    const __attribute__((address_space(1))) void* gp =
        reinterpret_cast<const __attribute__((address_space(1))) void*>(
            reinterpret_cast<uintptr_t>(g));
    __attribute__((address_space(3))) void* lp =
        reinterpret_cast<__attribute__((address_space(3))) void*>(
            static_cast<uintptr_t>(static_cast<uint32_t>(reinterpret_cast<uintptr_t>(l))));
    __builtin_amdgcn_global_load_lds(gp, lp, 16, 0, 0);
}

// ============================ pack kernels (proven) =================================

// xs: [n][ph][pw][c] i8, border rows/cols = 0
__global__ __launch_bounds__(256) void pack_xs_kernel(const float* __restrict__ x,
                                                      int8_t* __restrict__ xs) {
    int c  = threadIdx.x;
    int ph = blockIdx.x;
    int n  = blockIdx.y;
    int8_t* dst = xs + (((size_t)n * PH + ph) * PW) * 256 + c;
    if (ph == 0 || ph == PH - 1) {
        for (int pw = 0; pw < PW; ++pw) dst[(size_t)pw * 256] = 0;
        return;
    }
    int h = ph - 1;
    const float* src = x + ((size_t)(n * CC + c) * HH + h) * WW;
    dst[0] = 0;
    dst[(size_t)(PW - 1) * 256] = 0;
    for (int w = 0; w < WW; ++w) {
        float v = src[w];
        int8_t s = (v > 0.f) ? 1 : ((v < 0.f) ? -1 : 0);
        dst[(size_t)(w + 1) * 256] = s;
    }
}

// wsB: [o][t][c] i8 (t = kh*3+kw)
__global__ __launch_bounds__(256) void pack_wsB_kernel(const float* __restrict__ wgt,
                                                       int8_t* __restrict__ wsB) {
    int c = threadIdx.x;
    int o = blockIdx.x;
    const float* src = wgt + ((size_t)o * CC + c) * 9;
#pragma unroll
    for (int t = 0; t < 9; ++t) {
        float v = src[t];
        int8_t s = (v > 0.f) ? 1 : ((v < 0.f) ? -1 : 0);
        wsB[(size_t)o * KTOT + t * 256 + c] = s;
    }
}

// ============================ MFMA GEMM =============================================
// Block = 4 waves, tile 128 pixels x 128 out-ch, BK=64 (quarter-tap). K-tiles = 36.
// LDS: A[2][128][64] + B[2][128][64] = 32 KB, double-buffered, staged by
// global_load_lds(16B). Swizzle: LDS[row][chunk] = GLOBAL[row][chunk ^ ((row>>1)&3)]
// (chunk = 16B unit) applied on the staging SOURCE address and the ds_read address ->
// bank-conflict-free b128 reads. One __syncthreads per K-tile (2-phase schedule).

#define STAGE(BUF, KT) do {                                                  \
    const int _t = (KT) >> 2, _q = (KT) & 3;                                 \
    const uint32_t _at = (uint32_t)(((_t / 3) * PW + (_t % 3)) * 256 + _q * 64); \
    const uint32_t _bt = (uint32_t)(_t * 256 + _q * 64);                     \
    gload16(xs + (apb0 + _at), &Asm[BUF][wid * 1024]);                       \
    gload16(xs + (apb1 + _at), &Asm[BUF][4096 + wid * 1024]);                \
    gload16(wsB + (bpb0 + _bt), &Bsm[BUF][wid * 1024]);                      \
    gload16(wsB + (bpb1 + _bt), &Bsm[BUF][4096 + wid * 1024]);               \
} while (0)

#define COMPUTE(BUF) do {                                                    \
    i32x4 af0 = *(const i32x4*)&Asm[BUF][swzA0];                             \
    i32x4 af1 = *(const i32x4*)&Asm[BUF][swzA1];                             \
    i32x4 af2 = *(const i32x4*)&Asm[BUF][swzA2];                             \
    i32x4 af3 = *(const i32x4*)&Asm[BUF][swzA3];                             \
    i32x4 bf0 = *(const i32x4*)&Bsm[BUF][swzB0];                             \
    i32x4 bf1 = *(const i32x4*)&Bsm[BUF][swzB1];                             \
    i32x4 bf2 = *(const i32x4*)&Bsm[BUF][swzB2];                             \
    i32x4 bf3 = *(const i32x4*)&Bsm[BUF][swzB3];                             \
    acc[0][0] = __builtin_amdgcn_mfma_i32_16x16x64_i8(af0, bf0, acc[0][0], 0, 0, 0); \
    acc[0][1] = __builtin_amdgcn_mfma_i32_16x16x64_i8(af0, bf1, acc[0][1], 0, 0, 0); \
    acc[0][2] = __builtin_amdgcn_mfma_i32_16x16x64_i8(af0, bf2, acc[0][2], 0, 0, 0); \
    acc[0][3] = __builtin_amdgcn_mfma_i32_16x16x64_i8(af0, bf3, acc[0][3], 0, 0, 0); \
    acc[1][0] = __builtin_amdgcn_mfma_i32_16x16x64_i8(af1, bf0, acc[1][0], 0, 0, 0); \
    acc[1][1] = __builtin_amdgcn_mfma_i32_16x16x64_i8(af1, bf1, acc[1][1], 0, 0, 0); \
    acc[1][2] = __builtin_amdgcn_mfma_i32_16x16x64_i8(af1, bf2, acc[1][2], 0, 0, 0); \
    acc[1][3] = __builtin_amdgcn_mfma_i32_16x16x64_i8(af1, bf3, acc[1][3], 0, 0, 0); \
    acc[2][0] = __builtin_amdgcn_mfma_i32_16x16x64_i8(af2, bf0, acc[2][0], 0, 0, 0); \
    acc[2][1] = __builtin_amdgcn_mfma_i32_16x16x64_i8(af2, bf1, acc[2][1], 0, 0, 0); \
    acc[2][2] = __builtin_amdgcn_mfma_i32_16x16x64_i8(af2, bf2, acc[2][2], 0, 0, 0); \
    acc[2][3] = __builtin_amdgcn_mfma_i32_16x16x64_i8(af2, bf3, acc[2][3], 0, 0, 0); \
    acc[3][0] = __builtin_amdgcn_mfma_i32_16x16x64_i8(af3, bf0, acc[3][0], 0, 0, 0); \
    acc[3][1] = __builtin_amdgcn_mfma_i32_16x16x64_i8(af3, bf1, acc[3][1], 0, 0, 0); \
    acc[3][2] = __builtin_amdgcn_mfma_i32_16x16x64_i8(af3, bf2, acc[3][2], 0, 0, 0); \
    acc[3][3] = __builtin_amdgcn_mfma_i32_16x16x64_i8(af3, bf3, acc[3][3], 0, 0, 0); \
} while (0)

__global__ __launch_bounds__(256, 2) void bconv_mfma_kernel(const int8_t* __restrict__ xs,
                                                            const int8_t* __restrict__ wsB,
                                                            const float* __restrict__ bias,
                                                            float* __restrict__ out) {
    __shared__ __align__(16) int8_t Asm[2][128 * 64];   // 16 KB
    __shared__ __align__(16) int8_t Bsm[2][128 * 64];   // 16 KB

    const int b   = blockIdx.x;            // 0..1567
    const int nb  = b & 1;                 // N-block (128 ch)
    const int m   = b >> 1;                // M-tile (128 pixels)
    const int tid = threadIdx.x;
    const int l   = tid & 63;
    const int wid = tid >> 6;
    const int lg  = l >> 4;                // k-group 0..3
    const int lr  = l & 15;                // row (A) / col (B,C)
    const int wm  = wid & 1, wn = wid >> 1;

    const int M0  = m * 128;
    const int O0b = nb * 128;
    const int O0  = O0b + wn * 64;

    // ---- staging addresses: thread handles rows j*64 + (tid>>2), chunk tid&3 -------
    const int srow0 = tid >> 2;                       // j = 0 row
    const int g16   = (((tid & 3) ^ ((tid >> 3) & 3)) << 4);
    uint32_t apb0, apb1, bpb0, bpb1;
    {
        int p0 = M0 + srow0;
        int n0 = p0 / SS, sp0 = p0 - n0 * SS, h0 = sp0 / WW, w0 = sp0 - h0 * WW;
        apb0 = (uint32_t)(((n0 * PH + h0) * PW + w0) * 256 + g16);
        int p1 = M0 + 64 + srow0;
        int n1 = p1 / SS, sp1 = p1 - n1 * SS, h1 = sp1 / WW, w1 = sp1 - h1 * WW;
        apb1 = (uint32_t)(((n1 * PH + h1) * PW + w1) * 256 + g16);
        bpb0 = (uint32_t)((O0b + srow0) * KTOT + g16);
        bpb1 = (uint32_t)((O0b + 64 + srow0) * KTOT + g16);
    }

    // ---- ds_read offsets (swizzled): row*64 + ((lg ^ ((lr>>1)&3))<<4) --------------
    const int swz16 = ((lg ^ ((lr >> 1) & 3)) << 4);
    const int swzA0 = (wm * 64 + 0 * 16 + lr) * 64 + swz16;
    const int swzA1 = (wm * 64 + 1 * 16 + lr) * 64 + swz16;
    const int swzA2 = (wm * 64 + 2 * 16 + lr) * 64 + swz16;
    const int swzA3 = (wm * 64 + 3 * 16 + lr) * 64 + swz16;
    const int swzB0 = (wn * 64 + 0 * 16 + lr) * 64 + swz16;
    const int swzB1 = (wn * 64 + 1 * 16 + lr) * 64 + swz16;
    const int swzB2 = (wn * 64 + 2 * 16 + lr) * 64 + swz16;
    const int swzB3 = (wn * 64 + 3 * 16 + lr) * 64 + swz16;

    i32x4 acc[4][4];
#pragma unroll
    for (int s = 0; s < 4; ++s)
#pragma unroll
        for (int u = 0; u < 4; ++u)
            acc[s][u] = (i32x4){0, 0, 0, 0};

    // ---- 2-phase K-loop over 36 tiles of K=64 --------------------------------------
    STAGE(0, 0);
    __syncthreads();
#pragma unroll 1
    for (int kt = 0; kt < 36; kt += 2) {
        STAGE(1, kt + 1);                 // kt+1 <= 35 always (kt even, < 36)
        COMPUTE(0);
        __syncthreads();
        if (kt + 2 < 36) STAGE(0, kt + 2);
        COMPUTE(1);
        __syncthreads();
    }

    // ---- epilogue (bit-exact mapping proven in R6/R8) ------------------------------
    float bo[4];
#pragma unroll
    for (int u = 0; u < 4; ++u) bo[u] = bias[O0 + u * 16 + lr];

#pragma unroll
    for (int s = 0; s < 4; ++s) {
        int pst = M0 + wm * 64 + s * 16 + lg * 4;    // lane's 4 consecutive pixels
        int n   = pst / SS;
        int sp  = pst - n * SS;
#pragma unroll
        for (int u = 0; u < 4; ++u) {
            i32x4 a = acc[s][u];
            int o = O0 + u * 16 + lr;
            float v0 = (float)a.x + bo[u];
            float v1 = (float)a.y + bo[u];
            float v2 = (float)a.z + bo[u];
            float v3 = (float)a.w + bo[u];
            float4 r4;
            r4.x = (v0 > 0.f) ? 1.f : ((v0 < 0.f) ? -1.f : 0.f);
            r4.y = (v1 > 0.f) ? 1.f : ((v1 < 0.f) ? -1.f : 0.f);
            r4.z = (v2 > 0.f) ? 1.f : ((v2 < 0.f) ? -1.f : 0.f);
            r4.w = (v3 > 0.f) ? 1.f : ((v3 < 0.f) ? -1.f : 0.f);
            *(float4*)(out + ((size_t)(n * OO + o)) * SS + sp) = r4;
        }
    }
}

// ============================ fallback popcount path (R4, 163 us) ===================

#define SPAD (PH*PW)
#define CWN  4

__global__ __launch_bounds__(256) void pack_x_kernel(const float* __restrict__ x,
                                                     uint64_t* __restrict__ px) {
    int tid = threadIdx.x;
    int sp  = blockIdx.x * 256 + tid;
    int cw  = blockIdx.y;
    int n   = blockIdx.z;
    if (sp >= SPAD) return;
    int ph = sp / PW, pw_ = sp % PW;
    uint64_t* dst = px + (((size_t)n * CWN + cw) * SPAD + sp);
    if (ph == 0 || ph == PH - 1 || pw_ == 0 || pw_ == PW - 1) { *dst = 0ull; return; }
    int h = ph - 1, w = pw_ - 1;
    const float* src = x + ((size_t)(n * CC + cw * 64)) * SS + (h * WW + w);
    uint32_t lo = 0u, hi = 0u;
#pragma unroll
    for (int j = 0; j < 32; ++j) { float v = src[(size_t)j * SS];        lo |= (v > 0.0f ? 1u : 0u) << j; }
#pragma unroll
    for (int j = 0; j < 32; ++j) { float v = src[(size_t)(j + 32) * SS]; hi |= (v > 0.0f ? 1u : 0u) << j; }
    *dst = ((uint64_t)hi << 32) | (uint64_t)lo;
}

__global__ __launch_bounds__(256) void pack_w_kernel(const float* __restrict__ wgt,
                                                     uint64_t* __restrict__ pwb) {
    int lane = threadIdx.x & 63;
    int wave = threadIdx.x >> 6;
    int wi   = blockIdx.x * 4 + wave;
    if (wi >= OO * 9 * CWN) return;
    int o = wi / 36, rem = wi % 36, t = rem >> 2, cw = rem & 3;
    int c = cw * 64 + lane;
    float v = wgt[(size_t)(o * CC + c) * 9 + t];
    uint64_t m = __ballot(v > 0.0f);
    if (lane == 0) pwb[wi] = m;
}

__global__ __launch_bounds__(256) void build_k_kernel(const uint64_t* __restrict__ pwb,
                                                      int* __restrict__ ktab) {
    int o = threadIdx.x;
    int pops[9];
#pragma unroll
    for (int t = 0; t < 9; ++t) {
        int p = 0;
#pragma unroll
        for (int cw = 0; cw < 4; ++cw) p += __popcll(pwb[o * 36 + t * 4 + cw]);
        pops[t] = p;
    }
#pragma unroll
    for (int cls = 0; cls < 9; ++cls) {
        int vf = cls / 3, hf = cls % 3;
        int K = 9 * CC;
#pragma unroll
        for (int t = 0; t < 9; ++t) {
            int r = t / 3, k = t % 3;
            bool inv = (vf == 1 && r == 0) || (vf == 2 && r == 2) ||
                       (hf == 1 && k == 0) || (hf == 2 && k == 2);
            if (inv) K -= (CC - 2 * pops[t]);
        }
        ktab[cls * OO + o] = K;
    }
}

__global__ __launch_bounds__(256, 4) void bconv_kernel(const uint64_t* __restrict__ px,
                                                       const uint64_t* __restrict__ pwb,
                                                       const int* __restrict__ ktab,
                                                       const float* __restrict__ bias,
                                                       float* __restrict__ out) {
    int g = blockIdx.x * 256 + threadIdx.x;
    int n = g / SS;
    int sid = g - n * SS;
    int obase = blockIdx.y * 32;
    int h = sid / WW, w = sid - h * WW;
    int vf = (h == 0) ? 1 : ((h == HH - 1) ? 2 : 0);
    int hf = (w == 0) ? 1 : ((w == WW - 1) ? 2 : 0);
    const int* krow = ktab + (vf * 3 + hf) * OO + obase;
    const uint64_t* pb = px + (size_t)n * CWN * SPAD + h * PW + w;
    const uint32_t* wb = (const uint32_t*)pwb + (size_t)obase * 72;
    uint32_t acc[32];
#pragma unroll
    for (int i = 0; i < 32; ++i) acc[i] = 0u;
#pragma unroll 1
    for (int r = 0; r < 3; ++r) {
#pragma unroll 1
        for (int k = 0; k < 3; ++k) {
            int off = r * PW + k;
            uint64_t q0 = pb[off];
            uint64_t q1 = pb[SPAD + off];
            uint64_t q2 = pb[2 * SPAD + off];
            uint64_t q3 = pb[3 * SPAD + off];
            uint32_t pa0 = (uint32_t)q0, pa1 = (uint32_t)(q0 >> 32);
            uint32_t pa2 = (uint32_t)q1, pa3 = (uint32_t)(q1 >> 32);
            uint32_t pa4 = (uint32_t)q2, pa5 = (uint32_t)(q2 >> 32);
            uint32_t pa6 = (uint32_t)q3, pa7 = (uint32_t)(q3 >> 32);
            int t8 = (r * 3 + k) * 8;
#pragma unroll
            for (int oi = 0; oi < 32; ++oi) {
                const uint32_t* wv = wb + oi * 72 + t8;
                uint32_t a = acc[oi];
                a = __popc(pa0 ^ wv[0]) + a;
                a = __popc(pa1 ^ wv[1]) + a;
                a = __popc(pa2 ^ wv[2]) + a;
                a = __popc(pa3 ^ wv[3]) + a;
                a = __popc(pa4 ^ wv[4]) + a;
                a = __popc(pa5 ^ wv[5]) + a;
                a = __popc(pa6 ^ wv[6]) + a;
                a = __popc(pa7 ^ wv[7]) + a;
                acc[oi] = a;
            }
        }
    }
    float* orow = out + ((size_t)(n * OO + obase)) * SS + sid;
#pragma unroll
    for (int oi = 0; oi < 32; ++oi) {
        int s = krow[oi] - 2 * (int)acc[oi];
        float v = (float)s + bias[obase + oi];
        float res = (v > 0.0f) ? 1.0f : ((v < 0.0f) ? -1.0f : 0.0f);
        orow[(size_t)oi * SS] = res;
    }
}

// ============================ launch ================================================

extern "C" void kernel_launch(void* const* d_in, const int* in_sizes, int n_in,
                              void* d_out, int out_size, void* d_ws, size_t ws_size,
                              hipStream_t stream) {
    const float* x    = (const float*)d_in[0];
    const float* wgt  = (const float*)d_in[1];
    const float* bias = (const float*)d_in[2];
    float* out = (float*)d_out;

    const size_t wsB_bytes = (size_t)OO * KTOT;                 // 589,824
    const size_t xs_bytes  = (size_t)NB * PH * PW * 256;        // 27,557,888
    if (ws_size >= wsB_bytes + xs_bytes) {
        int8_t* wsB = (int8_t*)d_ws;
        int8_t* xs  = (int8_t*)d_ws + wsB_bytes;
        pack_xs_kernel<<<dim3(PH, NB), 256, 0, stream>>>(x, xs);
        pack_wsB_kernel<<<dim3(OO), 256, 0, stream>>>(wgt, wsB);
        const int n_blocks = (NB * SS / 128) * (OO / 128);      // 784 * 2 = 1568
        bconv_mfma_kernel<<<dim3(n_blocks), 256, 0, stream>>>(xs, wsB, bias, out);
    } else {
        // fallback: proven popcount path (R4)
        size_t px_bytes = (size_t)NB * CWN * SPAD * 8;
        size_t pw_off   = px_bytes;
        size_t pw_bytes = (size_t)OO * 9 * CWN * 8;
        size_t k_off    = pw_off + pw_bytes;
        uint64_t* px  = (uint64_t*)d_ws;
        uint64_t* pwb = (uint64_t*)((char*)d_ws + pw_off);
        int*      kt  = (int*)((char*)d_ws + k_off);
        dim3 gpx((SPAD + 255) / 256, CWN, NB);
        pack_x_kernel<<<gpx, 256, 0, stream>>>(x, px);
        int nwords = OO * 9 * CWN;
        pack_w_kernel<<<dim3((nwords + 3) / 4), 256, 0, stream>>>(wgt, pwb);
        build_k_kernel<<<dim3(1), 256, 0, stream>>>(pwb, kt);
        dim3 gcv(NB * SS / 256, OO / 32, 1);
        bconv_kernel<<<gcv, 256, 0, stream>>>(px, pwb, kt, bias, out);
    }
}

// Round 10
// 127.073 us; speedup vs baseline: 3.5211x; 1.0174x over previous
//
#include <hip/hip_runtime.h>
#include <stdint.h>

typedef __attribute__((ext_vector_type(4))) int i32x4;

// BinaryConv: out = sign(conv2d(sign(x), sign(w), pad=1) + bias)
// i8 MFMA implicit GEMM, LDS ring buffer (depth-2 prefetch) + counted vmcnt (T3/T4).
// M=100352 pixels, N=256 out-ch, K=2304 (9 taps x 256 ch). Exact i32 arithmetic.

#define NB 32
#define CC 256
#define HH 56
#define WW 56
#define OO 256
#define PH 58
#define PW 58
#define SS (HH*WW)      // 3136
#define KTOT 2304

// ---- async global->LDS, 16B per lane; dest = wave-uniform base + lane*16 -----------
__device__ __forceinline__ void gload16(const void* g, void* l) {
    const __attribute__((address_space(1))) void* gp =
        reinterpret_cast<const __attribute__((address_space(1))) void*>(
            reinterpret_cast<uintptr_t>(g));
    __attribute__((address_space(3))) void* lp =
        reinterpret_cast<__attribute__((address_space(3))) void*>(
            static_cast<uintptr_t>(static_cast<uint32_t>(reinterpret_cast<uintptr_t>(l))));
    __builtin_amdgcn_global_load_lds(gp, lp, 16, 0, 0);
}

#define WAITVM(N) asm volatile("s_waitcnt vmcnt(" #N ")" ::: "memory")
#define WAITLGKM0() asm volatile("s_waitcnt lgkmcnt(0)" ::: "memory")

// ============================ pack kernels (proven) =================================

// xs: [n][ph][pw][c] i8, border rows/cols = 0
__global__ __launch_bounds__(256) void pack_xs_kernel(const float* __restrict__ x,
                                                      int8_t* __restrict__ xs) {
    int c  = threadIdx.x;
    int ph = blockIdx.x;
    int n  = blockIdx.y;
    int8_t* dst = xs + (((size_t)n * PH + ph) * PW) * 256 + c;
    if (ph == 0 || ph == PH - 1) {
        for (int pw = 0; pw < PW; ++pw) dst[(size_t)pw * 256] = 0;
        return;
    }
    int h = ph - 1;
    const float* src = x + ((size_t)(n * CC + c) * HH + h) * WW;
    dst[0] = 0;
    dst[(size_t)(PW - 1) * 256] = 0;
    for (int w = 0; w < WW; ++w) {
        float v = src[w];
        int8_t s = (v > 0.f) ? 1 : ((v < 0.f) ? -1 : 0);
        dst[(size_t)(w + 1) * 256] = s;
    }
}

// wsB: [o][t][c] i8 (t = kh*3+kw)
__global__ __launch_bounds__(256) void pack_wsB_kernel(const float* __restrict__ wgt,
                                                       int8_t* __restrict__ wsB) {
    int c = threadIdx.x;
    int o = blockIdx.x;
    const float* src = wgt + ((size_t)o * CC + c) * 9;
#pragma unroll
    for (int t = 0; t < 9; ++t) {
        float v = src[t];
        int8_t s = (v > 0.f) ? 1 : ((v < 0.f) ? -1 : 0);
        wsB[(size_t)o * KTOT + t * 256 + c] = s;
    }
}

// ============================ MFMA GEMM =============================================
// Block = 4 waves, tile 128 pixels x 128 out-ch, BK=64. 36 K-tiles.
// LDS ring: 3 buffers x (A 8KB + B 8KB) = 48 KB. Iteration kt: issue STAGE(kt+2),
// s_waitcnt vmcnt(8) (tile kt's 4 loads retired, 8 prefetch loads stay IN FLIGHT
// across the barrier), raw s_barrier, COMPUTE(kt), lgkmcnt(0), s_barrier.
// Never vmcnt(0) in the main loop -- the R9 __syncthreads drain was the 2-phase tax.
// Swizzle (verified bit-exact R9): LDS[row][chunk] = GLOBAL[row][chunk ^ ((row>>1)&3)]
// on both the staging source and the ds_read address.

#define STAGE(BUF, KT) do {                                                  \
    const int _t = (KT) >> 2, _q = (KT) & 3;                                 \
    const uint32_t _at = (uint32_t)(((_t / 3) * PW + (_t % 3)) * 256 + _q * 64); \
    const uint32_t _bt = (uint32_t)(_t * 256 + _q * 64);                     \
    int8_t* _lb = lds8 + (BUF) * 16384 + wid * 1024;                         \
    gload16(xs + (apb0 + _at), _lb);                                         \
    gload16(xs + (apb1 + _at), _lb + 4096);                                  \
    gload16(wsB + (bpb0 + _bt), _lb + 8192);                                 \
    gload16(wsB + (bpb1 + _bt), _lb + 12288);                                \
} while (0)

#define COMPUTE(BUF) do {                                                    \
    const int8_t* _Ab = lds8 + (BUF) * 16384;                                \
    const int8_t* _Bb = _Ab + 8192;                                          \
    i32x4 af0 = *(const i32x4*)(_Ab + swzA0);                                \
    i32x4 af1 = *(const i32x4*)(_Ab + swzA1);                                \
    i32x4 af2 = *(const i32x4*)(_Ab + swzA2);                                \
    i32x4 af3 = *(const i32x4*)(_Ab + swzA3);                                \
    i32x4 bf0 = *(const i32x4*)(_Bb + swzB0);                                \
    i32x4 bf1 = *(const i32x4*)(_Bb + swzB1);                                \
    i32x4 bf2 = *(const i32x4*)(_Bb + swzB2);                                \
    i32x4 bf3 = *(const i32x4*)(_Bb + swzB3);                                \
    acc[0][0] = __builtin_amdgcn_mfma_i32_16x16x64_i8(af0, bf0, acc[0][0], 0, 0, 0); \
    acc[0][1] = __builtin_amdgcn_mfma_i32_16x16x64_i8(af0, bf1, acc[0][1], 0, 0, 0); \
    acc[0][2] = __builtin_amdgcn_mfma_i32_16x16x64_i8(af0, bf2, acc[0][2], 0, 0, 0); \
    acc[0][3] = __builtin_amdgcn_mfma_i32_16x16x64_i8(af0, bf3, acc[0][3], 0, 0, 0); \
    acc[1][0] = __builtin_amdgcn_mfma_i32_16x16x64_i8(af1, bf0, acc[1][0], 0, 0, 0); \
    acc[1][1] = __builtin_amdgcn_mfma_i32_16x16x64_i8(af1, bf1, acc[1][1], 0, 0, 0); \
    acc[1][2] = __builtin_amdgcn_mfma_i32_16x16x64_i8(af1, bf2, acc[1][2], 0, 0, 0); \
    acc[1][3] = __builtin_amdgcn_mfma_i32_16x16x64_i8(af1, bf3, acc[1][3], 0, 0, 0); \
    acc[2][0] = __builtin_amdgcn_mfma_i32_16x16x64_i8(af2, bf0, acc[2][0], 0, 0, 0); \
    acc[2][1] = __builtin_amdgcn_mfma_i32_16x16x64_i8(af2, bf1, acc[2][1], 0, 0, 0); \
    acc[2][2] = __builtin_amdgcn_mfma_i32_16x16x64_i8(af2, bf2, acc[2][2], 0, 0, 0); \
    acc[2][3] = __builtin_amdgcn_mfma_i32_16x16x64_i8(af2, bf3, acc[2][3], 0, 0, 0); \
    acc[3][0] = __builtin_amdgcn_mfma_i32_16x16x64_i8(af3, bf0, acc[3][0], 0, 0, 0); \
    acc[3][1] = __builtin_amdgcn_mfma_i32_16x16x64_i8(af3, bf1, acc[3][1], 0, 0, 0); \
    acc[3][2] = __builtin_amdgcn_mfma_i32_16x16x64_i8(af3, bf2, acc[3][2], 0, 0, 0); \
    acc[3][3] = __builtin_amdgcn_mfma_i32_16x16x64_i8(af3, bf3, acc[3][3], 0, 0, 0); \
} while (0)

__global__ __launch_bounds__(256, 2) void bconv_mfma_kernel(const int8_t* __restrict__ xs,
                                                            const int8_t* __restrict__ wsB,
                                                            const float* __restrict__ bias,
                                                            float* __restrict__ out) {
    __shared__ __align__(16) int8_t lds8[3 * 16384];    // 48 KB ring

    const int b   = blockIdx.x;            // 0..1567
    const int nb  = b & 1;                 // N-block (128 ch)
    const int m   = b >> 1;                // M-tile (128 pixels)
    const int tid = threadIdx.x;
    const int l   = tid & 63;
    const int wid = tid >> 6;
    const int lg  = l >> 4;                // k-group 0..3
    const int lr  = l & 15;                // row (A) / col (B,C)
    const int wm  = wid & 1, wn = wid >> 1;

    const int M0  = m * 128;
    const int O0b = nb * 128;
    const int O0  = O0b + wn * 64;

    // ---- staging addresses: thread handles rows j*64 + (tid>>2), chunk tid&3 -------
    const int srow0 = tid >> 2;
    const int g16   = (((tid & 3) ^ ((tid >> 3) & 3)) << 4);
    uint32_t apb0, apb1, bpb0, bpb1;
    {
        int p0 = M0 + srow0;
        int n0 = p0 / SS, sp0 = p0 - n0 * SS, h0 = sp0 / WW, w0 = sp0 - h0 * WW;
        apb0 = (uint32_t)(((n0 * PH + h0) * PW + w0) * 256 + g16);
        int p1 = M0 + 64 + srow0;
        int n1 = p1 / SS, sp1 = p1 - n1 * SS, h1 = sp1 / WW, w1 = sp1 - h1 * WW;
        apb1 = (uint32_t)(((n1 * PH + h1) * PW + w1) * 256 + g16);
        bpb0 = (uint32_t)((O0b + srow0) * KTOT + g16);
        bpb1 = (uint32_t)((O0b + 64 + srow0) * KTOT + g16);
    }

    // ---- ds_read offsets (swizzled) ------------------------------------------------
    const int swz16 = ((lg ^ ((lr >> 1) & 3)) << 4);
    const int swzA0 = (wm * 64 + 0 * 16 + lr) * 64 + swz16;
    const int swzA1 = (wm * 64 + 1 * 16 + lr) * 64 + swz16;
    const int swzA2 = (wm * 64 + 2 * 16 + lr) * 64 + swz16;
    const int swzA3 = (wm * 64 + 3 * 16 + lr) * 64 + swz16;
    const int swzB0 = (wn * 64 + 0 * 16 + lr) * 64 + swz16;
    const int swzB1 = (wn * 64 + 1 * 16 + lr) * 64 + swz16;
    const int swzB2 = (wn * 64 + 2 * 16 + lr) * 64 + swz16;
    const int swzB3 = (wn * 64 + 3 * 16 + lr) * 64 + swz16;

    i32x4 acc[4][4];
#pragma unroll
    for (int s = 0; s < 4; ++s)
#pragma unroll
        for (int u = 0; u < 4; ++u)
            acc[s][u] = (i32x4){0, 0, 0, 0};

    // ---- ring K-loop: 36 tiles, depth-2 prefetch, counted vmcnt ---------------------
    STAGE(0, 0);
    STAGE(1, 1);                           // 8 loads/thread outstanding
#pragma unroll 1
    for (int kt = 0; kt < 34; ++kt) {
        const int cur = kt % 3;
        const int nxt = (kt + 2) % 3;
        STAGE(nxt, kt + 2);                // 12 outstanding
        WAITVM(8);                         // tile kt retired; kt+1/kt+2 stay in flight
        __builtin_amdgcn_s_barrier();
        __builtin_amdgcn_sched_barrier(0);
        COMPUTE(cur);
        WAITLGKM0();                       // this wave's ds_reads of buf cur consumed
        __builtin_amdgcn_sched_barrier(0);
        __builtin_amdgcn_s_barrier();      // gates next iteration's overwrite of cur-1
    }
    // kt = 34 (buf 1): 8 outstanding
    WAITVM(4);
    __builtin_amdgcn_s_barrier();
    __builtin_amdgcn_sched_barrier(0);
    COMPUTE(1);
    WAITLGKM0();
    __builtin_amdgcn_s_barrier();
    // kt = 35 (buf 2): 4 outstanding
    WAITVM(0);
    __builtin_amdgcn_s_barrier();
    __builtin_amdgcn_sched_barrier(0);
    COMPUTE(2);

    // ---- epilogue (bit-exact mapping proven in R6/R8/R9) ---------------------------
    float bo[4];
#pragma unroll
    for (int u = 0; u < 4; ++u) bo[u] = bias[O0 + u * 16 + lr];

#pragma unroll
    for (int s = 0; s < 4; ++s) {
        int pst = M0 + wm * 64 + s * 16 + lg * 4;
        int n   = pst / SS;
        int sp  = pst - n * SS;
#pragma unroll
        for (int u = 0; u < 4; ++u) {
            i32x4 a = acc[s][u];
            int o = O0 + u * 16 + lr;
            float v0 = (float)a.x + bo[u];
            float v1 = (float)a.y + bo[u];
            float v2 = (float)a.z + bo[u];
            float v3 = (float)a.w + bo[u];
            float4 r4;
            r4.x = (v0 > 0.f) ? 1.f : ((v0 < 0.f) ? -1.f : 0.f);
            r4.y = (v1 > 0.f) ? 1.f : ((v1 < 0.f) ? -1.f : 0.f);
            r4.z = (v2 > 0.f) ? 1.f : ((v2 < 0.f) ? -1.f : 0.f);
            r4.w = (v3 > 0.f) ? 1.f : ((v3 < 0.f) ? -1.f : 0.f);
            *(float4*)(out + ((size_t)(n * OO + o)) * SS + sp) = r4;
        }
    }
}

// ============================ fallback popcount path (R4, 163 us) ===================

#define SPAD (PH*PW)
#define CWN  4

__global__ __launch_bounds__(256) void pack_x_kernel(const float* __restrict__ x,
                                                     uint64_t* __restrict__ px) {
    int tid = threadIdx.x;
    int sp  = blockIdx.x * 256 + tid;
    int cw  = blockIdx.y;
    int n   = blockIdx.z;
    if (sp >= SPAD) return;
    int ph = sp / PW, pw_ = sp % PW;
    uint64_t* dst = px + (((size_t)n * CWN + cw) * SPAD + sp);
    if (ph == 0 || ph == PH - 1 || pw_ == 0 || pw_ == PW - 1) { *dst = 0ull; return; }
    int h = ph - 1, w = pw_ - 1;
    const float* src = x + ((size_t)(n * CC + cw * 64)) * SS + (h * WW + w);
    uint32_t lo = 0u, hi = 0u;
#pragma unroll
    for (int j = 0; j < 32; ++j) { float v = src[(size_t)j * SS];        lo |= (v > 0.0f ? 1u : 0u) << j; }
#pragma unroll
    for (int j = 0; j < 32; ++j) { float v = src[(size_t)(j + 32) * SS]; hi |= (v > 0.0f ? 1u : 0u) << j; }
    *dst = ((uint64_t)hi << 32) | (uint64_t)lo;
}

__global__ __launch_bounds__(256) void pack_w_kernel(const float* __restrict__ wgt,
                                                     uint64_t* __restrict__ pwb) {
    int lane = threadIdx.x & 63;
    int wave = threadIdx.x >> 6;
    int wi   = blockIdx.x * 4 + wave;
    if (wi >= OO * 9 * CWN) return;
    int o = wi / 36, rem = wi % 36, t = rem >> 2, cw = rem & 3;
    int c = cw * 64 + lane;
    float v = wgt[(size_t)(o * CC + c) * 9 + t];
    uint64_t m = __ballot(v > 0.0f);
    if (lane == 0) pwb[wi] = m;
}

__global__ __launch_bounds__(256) void build_k_kernel(const uint64_t* __restrict__ pwb,
                                                      int* __restrict__ ktab) {
    int o = threadIdx.x;
    int pops[9];
#pragma unroll
    for (int t = 0; t < 9; ++t) {
        int p = 0;
#pragma unroll
        for (int cw = 0; cw < 4; ++cw) p += __popcll(pwb[o * 36 + t * 4 + cw]);
        pops[t] = p;
    }
#pragma unroll
    for (int cls = 0; cls < 9; ++cls) {
        int vf = cls / 3, hf = cls % 3;
        int K = 9 * CC;
#pragma unroll
        for (int t = 0; t < 9; ++t) {
            int r = t / 3, k = t % 3;
            bool inv = (vf == 1 && r == 0) || (vf == 2 && r == 2) ||
                       (hf == 1 && k == 0) || (hf == 2 && k == 2);
            if (inv) K -= (CC - 2 * pops[t]);
        }
        ktab[cls * OO + o] = K;
    }
}

__global__ __launch_bounds__(256, 4) void bconv_kernel(const uint64_t* __restrict__ px,
                                                       const uint64_t* __restrict__ pwb,
                                                       const int* __restrict__ ktab,
                                                       const float* __restrict__ bias,
                                                       float* __restrict__ out) {
    int g = blockIdx.x * 256 + threadIdx.x;
    int n = g / SS;
    int sid = g - n * SS;
    int obase = blockIdx.y * 32;
    int h = sid / WW, w = sid - h * WW;
    int vf = (h == 0) ? 1 : ((h == HH - 1) ? 2 : 0);
    int hf = (w == 0) ? 1 : ((w == WW - 1) ? 2 : 0);
    const int* krow = ktab + (vf * 3 + hf) * OO + obase;
    const uint64_t* pb = px + (size_t)n * CWN * SPAD + h * PW + w;
    const uint32_t* wb = (const uint32_t*)pwb + (size_t)obase * 72;
    uint32_t acc[32];
#pragma unroll
    for (int i = 0; i < 32; ++i) acc[i] = 0u;
#pragma unroll 1
    for (int r = 0; r < 3; ++r) {
#pragma unroll 1
        for (int k = 0; k < 3; ++k) {
            int off = r * PW + k;
            uint64_t q0 = pb[off];
            uint64_t q1 = pb[SPAD + off];
            uint64_t q2 = pb[2 * SPAD + off];
            uint64_t q3 = pb[3 * SPAD + off];
            uint32_t pa0 = (uint32_t)q0, pa1 = (uint32_t)(q0 >> 32);
            uint32_t pa2 = (uint32_t)q1, pa3 = (uint32_t)(q1 >> 32);
            uint32_t pa4 = (uint32_t)q2, pa5 = (uint32_t)(q2 >> 32);
            uint32_t pa6 = (uint32_t)q3, pa7 = (uint32_t)(q3 >> 32);
            int t8 = (r * 3 + k) * 8;
#pragma unroll
            for (int oi = 0; oi < 32; ++oi) {
                const uint32_t* wv = wb + oi * 72 + t8;
                uint32_t a = acc[oi];
                a = __popc(pa0 ^ wv[0]) + a;
                a = __popc(pa1 ^ wv[1]) + a;
                a = __popc(pa2 ^ wv[2]) + a;
                a = __popc(pa3 ^ wv[3]) + a;
                a = __popc(pa4 ^ wv[4]) + a;
                a = __popc(pa5 ^ wv[5]) + a;
                a = __popc(pa6 ^ wv[6]) + a;
                a = __popc(pa7 ^ wv[7]) + a;
                acc[oi] = a;
            }
        }
    }
    float* orow = out + ((size_t)(n * OO + obase)) * SS + sid;
#pragma unroll
    for (int oi = 0; oi < 32; ++oi) {
        int s = krow[oi] - 2 * (int)acc[oi];
        float v = (float)s + bias[obase + oi];
        float res = (v > 0.0f) ? 1.0f : ((v < 0.0f) ? -1.0f : 0.0f);
        orow[(size_t)oi * SS] = res;
    }
}

// ============================ launch ================================================

extern "C" void kernel_launch(void* const* d_in, const int* in_sizes, int n_in,
                              void* d_out, int out_size, void* d_ws, size_t ws_size,
                              hipStream_t stream) {
    const float* x    = (const float*)d_in[0];
    const float* wgt  = (const float*)d_in[1];
    const float* bias = (const float*)d_in[2];
    float* out = (float*)d_out;

    const size_t wsB_bytes = (size_t)OO * KTOT;                 // 589,824
    const size_t xs_bytes  = (size_t)NB * PH * PW * 256;        // 27,557,888
    if (ws_size >= wsB_bytes + xs_bytes) {
        int8_t* wsB = (int8_t*)d_ws;
        int8_t* xs  = (int8_t*)d_ws + wsB_bytes;
        pack_xs_kernel<<<dim3(PH, NB), 256, 0, stream>>>(x, xs);
        pack_wsB_kernel<<<dim3(OO), 256, 0, stream>>>(wgt, wsB);
        const int n_blocks = (NB * SS / 128) * (OO / 128);      // 784 * 2 = 1568
        bconv_mfma_kernel<<<dim3(n_blocks), 256, 0, stream>>>(xs, wsB, bias, out);
    } else {
        // fallback: proven popcount path (R4)
        size_t px_bytes = (size_t)NB * CWN * SPAD * 8;
        size_t pw_off   = px_bytes;
        size_t pw_bytes = (size_t)OO * 9 * CWN * 8;
        size_t k_off    = pw_off + pw_bytes;
        uint64_t* px  = (uint64_t*)d_ws;
        uint64_t* pwb = (uint64_t*)((char*)d_ws + pw_off);
        int*      kt  = (int*)((char*)d_ws + k_off);
        dim3 gpx((SPAD + 255) / 256, CWN, NB);
        pack_x_kernel<<<gpx, 256, 0, stream>>>(x, px);
        int nwords = OO * 9 * CWN;
        pack_w_kernel<<<dim3((nwords + 3) / 4), 256, 0, stream>>>(wgt, pwb);
        build_k_kernel<<<dim3(1), 256, 0, stream>>>(pwb, kt);
        dim3 gcv(NB * SS / 256, OO / 32, 1);
        bconv_kernel<<<gcv, 256, 0, stream>>>(px, pwb, kt, bias, out);
    }
}

// Round 11
// 117.171 us; speedup vs baseline: 3.8187x; 1.0845x over previous
//
#include <hip/hip_runtime.h>
#include <stdint.h>

typedef __attribute__((ext_vector_type(4))) int i32x4;

// BinaryConv: out = sign(conv2d(sign(x), sign(w), pad=1) + bias)
// i8 MFMA implicit GEMM. Tile 128 pixels x 256 out-ch (BN = whole N -> A fetched once),
// BK=64, 36 K-tiles, dbuf LDS + counted vmcnt. 32 MFMA per wave per barrier interval.
// M=100352, N=256, K=2304. Exact i32 arithmetic.

#define NB 32
#define CC 256
#define HH 56
#define WW 56
#define OO 256
#define PH 58
#define PW 58
#define SS (HH*WW)      // 3136
#define KTOT 2304

// ---- async global->LDS, 16B per lane; dest = wave-uniform base + lane*16 -----------
__device__ __forceinline__ void gload16(const void* g, void* l) {
    const __attribute__((address_space(1))) void* gp =
        reinterpret_cast<const __attribute__((address_space(1))) void*>(
            reinterpret_cast<uintptr_t>(g));
    __attribute__((address_space(3))) void* lp =
        reinterpret_cast<__attribute__((address_space(3))) void*>(
            static_cast<uintptr_t>(static_cast<uint32_t>(reinterpret_cast<uintptr_t>(l))));
    __builtin_amdgcn_global_load_lds(gp, lp, 16, 0, 0);
}

#define WAITVM(N) asm volatile("s_waitcnt vmcnt(" #N ")" ::: "memory")
#define WAITLGKM0() asm volatile("s_waitcnt lgkmcnt(0)" ::: "memory")

// ============================ pack kernels ==========================================

// xs: [n][ph][pw][c] i8, border rows/cols = 0. Reads vectorized float4 x14 per row.
__global__ __launch_bounds__(256) void pack_xs_kernel(const float* __restrict__ x,
                                                      int8_t* __restrict__ xs) {
    int c  = threadIdx.x;
    int ph = blockIdx.x;
    int n  = blockIdx.y;
    int8_t* dst = xs + (((size_t)n * PH + ph) * PW) * 256 + c;
    if (ph == 0 || ph == PH - 1) {
        for (int pw = 0; pw < PW; ++pw) dst[(size_t)pw * 256] = 0;
        return;
    }
    int h = ph - 1;
    const float4* src4 = (const float4*)(x + ((size_t)(n * CC + c) * HH + h) * WW);
    float4 rowv[14];
#pragma unroll
    for (int i = 0; i < 14; ++i) rowv[i] = src4[i];
    dst[0] = 0;
    dst[(size_t)(PW - 1) * 256] = 0;
    const float* rv = (const float*)rowv;
#pragma unroll
    for (int w = 0; w < 56; ++w) {
        float v = rv[w];
        int8_t s = (v > 0.f) ? 1 : ((v < 0.f) ? -1 : 0);
        dst[(size_t)(w + 1) * 256] = s;
    }
}

// wsB: [o][t][c] i8 (t = kh*3+kw)
__global__ __launch_bounds__(256) void pack_wsB_kernel(const float* __restrict__ wgt,
                                                       int8_t* __restrict__ wsB) {
    int c = threadIdx.x;
    int o = blockIdx.x;
    const float* src = wgt + ((size_t)o * CC + c) * 9;
#pragma unroll
    for (int t = 0; t < 9; ++t) {
        float v = src[t];
        int8_t s = (v > 0.f) ? 1 : ((v < 0.f) ? -1 : 0);
        wsB[(size_t)o * KTOT + t * 256 + c] = s;
    }
}

// ============================ MFMA GEMM =============================================
// Block = 4 waves (2M x 2N), tile 128 pixels x 256 out-ch, BK=64. 36 K-tiles.
// LDS: A[2][128*64]=16KB + B[2][256*64]=32KB = 48KB dbuf. STAGE = 6 gload16/thread.
// Schedule per tile (R9/R10-proven sync): STAGE(next) -> vmcnt(6) -> barrier ->
// COMPUTE (32 MFMA/wave) -> lgkmcnt(0) -> barrier. Counted vmcnt keeps next tile's
// 6 loads in flight across the barrier. Swizzle (bit-exact since R9):
// LDS[row][chunk] = GLOBAL[row][chunk ^ ((row>>1)&3)], staging source + ds_read addr.

#define STAGE(BUF, KT) do {                                                  \
    const int _t = (KT) >> 2, _q = (KT) & 3;                                 \
    const uint32_t _at = (uint32_t)(((_t / 3) * PW + (_t % 3)) * 256 + _q * 64); \
    const uint32_t _bt = (uint32_t)(_t * 256 + _q * 64);                     \
    gload16(xs + (apb0 + _at), &Asm[BUF][wid * 1024]);                       \
    gload16(xs + (apb1 + _at), &Asm[BUF][4096 + wid * 1024]);                \
    gload16(wsB + (bpb0 + _bt), &Bsm[BUF][wid * 1024]);                      \
    gload16(wsB + (bpb1 + _bt), &Bsm[BUF][4096 + wid * 1024]);               \
    gload16(wsB + (bpb2 + _bt), &Bsm[BUF][8192 + wid * 1024]);               \
    gload16(wsB + (bpb3 + _bt), &Bsm[BUF][12288 + wid * 1024]);              \
} while (0)

#define COMPUTE(BUF) do {                                                    \
    const int8_t* _Ab = &Asm[BUF][0];                                        \
    const int8_t* _Bb = &Bsm[BUF][0];                                        \
    i32x4 af[4], bf[8];                                                      \
    _Pragma("unroll")                                                        \
    for (int _s = 0; _s < 4; ++_s) af[_s] = *(const i32x4*)(_Ab + swzA[_s]); \
    _Pragma("unroll")                                                        \
    for (int _u = 0; _u < 8; ++_u) bf[_u] = *(const i32x4*)(_Bb + swzB[_u]); \
    _Pragma("unroll")                                                        \
    for (int _s = 0; _s < 4; ++_s) {                                         \
        _Pragma("unroll")                                                    \
        for (int _u = 0; _u < 8; ++_u)                                       \
            acc[_s][_u] = __builtin_amdgcn_mfma_i32_16x16x64_i8(af[_s], bf[_u], acc[_s][_u], 0, 0, 0); \
    }                                                                        \
} while (0)

__global__ __launch_bounds__(256, 2) void bconv_mfma_kernel(const int8_t* __restrict__ xs,
                                                            const int8_t* __restrict__ wsB,
                                                            const float* __restrict__ bias,
                                                            float* __restrict__ out) {
    __shared__ __align__(16) int8_t Asm[2][128 * 64];   // 16 KB
    __shared__ __align__(16) int8_t Bsm[2][256 * 64];   // 32 KB

    const int m   = blockIdx.x;            // 0..783 M-tile (BN = whole N)
    const int tid = threadIdx.x;
    const int l   = tid & 63;
    const int wid = tid >> 6;
    const int lg  = l >> 4;                // k-group 0..3
    const int lr  = l & 15;                // row (A) / col (B,C)
    const int wm  = wid & 1, wn = wid >> 1;

    const int M0 = m * 128;

    // ---- staging addresses: thread handles row i*64 + (tid>>2), chunk tid&3 --------
    const int srow0 = tid >> 2;
    const int g16   = (((tid & 3) ^ ((tid >> 3) & 3)) << 4);
    uint32_t apb0, apb1, bpb0, bpb1, bpb2, bpb3;
    {
        int p0 = M0 + srow0;
        int n0 = p0 / SS, sp0 = p0 - n0 * SS, h0 = sp0 / WW, w0 = sp0 - h0 * WW;
        apb0 = (uint32_t)(((n0 * PH + h0) * PW + w0) * 256 + g16);
        int p1 = M0 + 64 + srow0;
        int n1 = p1 / SS, sp1 = p1 - n1 * SS, h1 = sp1 / WW, w1 = sp1 - h1 * WW;
        apb1 = (uint32_t)(((n1 * PH + h1) * PW + w1) * 256 + g16);
        bpb0 = (uint32_t)((srow0) * KTOT + g16);
        bpb1 = (uint32_t)((64 + srow0) * KTOT + g16);
        bpb2 = (uint32_t)((128 + srow0) * KTOT + g16);
        bpb3 = (uint32_t)((192 + srow0) * KTOT + g16);
    }

    // ---- ds_read offsets (swizzled) ------------------------------------------------
    const int swz16 = ((lg ^ ((lr >> 1) & 3)) << 4);
    int swzA[4], swzB[8];
#pragma unroll
    for (int s = 0; s < 4; ++s) swzA[s] = (wm * 64 + s * 16 + lr) * 64 + swz16;
#pragma unroll
    for (int u = 0; u < 8; ++u) swzB[u] = (wn * 128 + u * 16 + lr) * 64 + swz16;

    i32x4 acc[4][8];
#pragma unroll
    for (int s = 0; s < 4; ++s)
#pragma unroll
        for (int u = 0; u < 8; ++u)
            acc[s][u] = (i32x4){0, 0, 0, 0};

    // ---- K-loop: 36 tiles, dbuf, counted vmcnt (6 loads stay in flight) ------------
    STAGE(0, 0);
    int cur = 0;
#pragma unroll 1
    for (int kt = 0; kt < 35; ++kt) {
        STAGE(cur ^ 1, kt + 1);            // 12 outstanding
        WAITVM(6);                         // tile kt landed; kt+1 stays in flight
        __builtin_amdgcn_s_barrier();
        __builtin_amdgcn_sched_barrier(0);
        COMPUTE(cur);
        WAITLGKM0();
        __builtin_amdgcn_sched_barrier(0);
        __builtin_amdgcn_s_barrier();      // gates next STAGE's overwrite of cur
        cur ^= 1;
    }
    WAITVM(0);
    __builtin_amdgcn_s_barrier();
    __builtin_amdgcn_sched_barrier(0);
    COMPUTE(cur);

    // ---- epilogue (bit-exact mapping proven R6/R8/R9/R10) --------------------------
    float bo[8];
#pragma unroll
    for (int u = 0; u < 8; ++u) bo[u] = bias[wn * 128 + u * 16 + lr];

#pragma unroll
    for (int s = 0; s < 4; ++s) {
        int pst = M0 + wm * 64 + s * 16 + lg * 4;
        int n   = pst / SS;
        int sp  = pst - n * SS;
#pragma unroll
        for (int u = 0; u < 8; ++u) {
            i32x4 a = acc[s][u];
            int o = wn * 128 + u * 16 + lr;
            float v0 = (float)a.x + bo[u];
            float v1 = (float)a.y + bo[u];
            float v2 = (float)a.z + bo[u];
            float v3 = (float)a.w + bo[u];
            float4 r4;
            r4.x = (v0 > 0.f) ? 1.f : ((v0 < 0.f) ? -1.f : 0.f);
            r4.y = (v1 > 0.f) ? 1.f : ((v1 < 0.f) ? -1.f : 0.f);
            r4.z = (v2 > 0.f) ? 1.f : ((v2 < 0.f) ? -1.f : 0.f);
            r4.w = (v3 > 0.f) ? 1.f : ((v3 < 0.f) ? -1.f : 0.f);
            *(float4*)(out + ((size_t)(n * OO + o)) * SS + sp) = r4;
        }
    }
}

// ============================ fallback popcount path (R4, 163 us) ===================

#define SPAD (PH*PW)
#define CWN  4

__global__ __launch_bounds__(256) void pack_x_kernel(const float* __restrict__ x,
                                                     uint64_t* __restrict__ px) {
    int tid = threadIdx.x;
    int sp  = blockIdx.x * 256 + tid;
    int cw  = blockIdx.y;
    int n   = blockIdx.z;
    if (sp >= SPAD) return;
    int ph = sp / PW, pw_ = sp % PW;
    uint64_t* dst = px + (((size_t)n * CWN + cw) * SPAD + sp);
    if (ph == 0 || ph == PH - 1 || pw_ == 0 || pw_ == PW - 1) { *dst = 0ull; return; }
    int h = ph - 1, w = pw_ - 1;
    const float* src = x + ((size_t)(n * CC + cw * 64)) * SS + (h * WW + w);
    uint32_t lo = 0u, hi = 0u;
#pragma unroll
    for (int j = 0; j < 32; ++j) { float v = src[(size_t)j * SS];        lo |= (v > 0.0f ? 1u : 0u) << j; }
#pragma unroll
    for (int j = 0; j < 32; ++j) { float v = src[(size_t)(j + 32) * SS]; hi |= (v > 0.0f ? 1u : 0u) << j; }
    *dst = ((uint64_t)hi << 32) | (uint64_t)lo;
}

__global__ __launch_bounds__(256) void pack_w_kernel(const float* __restrict__ wgt,
                                                     uint64_t* __restrict__ pwb) {
    int lane = threadIdx.x & 63;
    int wave = threadIdx.x >> 6;
    int wi   = blockIdx.x * 4 + wave;
    if (wi >= OO * 9 * CWN) return;
    int o = wi / 36, rem = wi % 36, t = rem >> 2, cw = rem & 3;
    int c = cw * 64 + lane;
    float v = wgt[(size_t)(o * CC + c) * 9 + t];
    uint64_t m = __ballot(v > 0.0f);
    if (lane == 0) pwb[wi] = m;
}

__global__ __launch_bounds__(256) void build_k_kernel(const uint64_t* __restrict__ pwb,
                                                      int* __restrict__ ktab) {
    int o = threadIdx.x;
    int pops[9];
#pragma unroll
    for (int t = 0; t < 9; ++t) {
        int p = 0;
#pragma unroll
        for (int cw = 0; cw < 4; ++cw) p += __popcll(pwb[o * 36 + t * 4 + cw]);
        pops[t] = p;
    }
#pragma unroll
    for (int cls = 0; cls < 9; ++cls) {
        int vf = cls / 3, hf = cls % 3;
        int K = 9 * CC;
#pragma unroll
        for (int t = 0; t < 9; ++t) {
            int r = t / 3, k = t % 3;
            bool inv = (vf == 1 && r == 0) || (vf == 2 && r == 2) ||
                       (hf == 1 && k == 0) || (hf == 2 && k == 2);
            if (inv) K -= (CC - 2 * pops[t]);
        }
        ktab[cls * OO + o] = K;
    }
}

__global__ __launch_bounds__(256, 4) void bconv_kernel(const uint64_t* __restrict__ px,
                                                       const uint64_t* __restrict__ pwb,
                                                       const int* __restrict__ ktab,
                                                       const float* __restrict__ bias,
                                                       float* __restrict__ out) {
    int g = blockIdx.x * 256 + threadIdx.x;
    int n = g / SS;
    int sid = g - n * SS;
    int obase = blockIdx.y * 32;
    int h = sid / WW, w = sid - h * WW;
    int vf = (h == 0) ? 1 : ((h == HH - 1) ? 2 : 0);
    int hf = (w == 0) ? 1 : ((w == WW - 1) ? 2 : 0);
    const int* krow = ktab + (vf * 3 + hf) * OO + obase;
    const uint64_t* pb = px + (size_t)n * CWN * SPAD + h * PW + w;
    const uint32_t* wb = (const uint32_t*)pwb + (size_t)obase * 72;
    uint32_t acc[32];
#pragma unroll
    for (int i = 0; i < 32; ++i) acc[i] = 0u;
#pragma unroll 1
    for (int r = 0; r < 3; ++r) {
#pragma unroll 1
        for (int k = 0; k < 3; ++k) {
            int off = r * PW + k;
            uint64_t q0 = pb[off];
            uint64_t q1 = pb[SPAD + off];
            uint64_t q2 = pb[2 * SPAD + off];
            uint64_t q3 = pb[3 * SPAD + off];
            uint32_t pa0 = (uint32_t)q0, pa1 = (uint32_t)(q0 >> 32);
            uint32_t pa2 = (uint32_t)q1, pa3 = (uint32_t)(q1 >> 32);
            uint32_t pa4 = (uint32_t)q2, pa5 = (uint32_t)(q2 >> 32);
            uint32_t pa6 = (uint32_t)q3, pa7 = (uint32_t)(q3 >> 32);
            int t8 = (r * 3 + k) * 8;
#pragma unroll
            for (int oi = 0; oi < 32; ++oi) {
                const uint32_t* wv = wb + oi * 72 + t8;
                uint32_t a = acc[oi];
                a = __popc(pa0 ^ wv[0]) + a;
                a = __popc(pa1 ^ wv[1]) + a;
                a = __popc(pa2 ^ wv[2]) + a;
                a = __popc(pa3 ^ wv[3]) + a;
                a = __popc(pa4 ^ wv[4]) + a;
                a = __popc(pa5 ^ wv[5]) + a;
                a = __popc(pa6 ^ wv[6]) + a;
                a = __popc(pa7 ^ wv[7]) + a;
                acc[oi] = a;
            }
        }
    }
    float* orow = out + ((size_t)(n * OO + obase)) * SS + sid;
#pragma unroll
    for (int oi = 0; oi < 32; ++oi) {
        int s = krow[oi] - 2 * (int)acc[oi];
        float v = (float)s + bias[obase + oi];
        float res = (v > 0.0f) ? 1.0f : ((v < 0.0f) ? -1.0f : 0.0f);
        orow[(size_t)oi * SS] = res;
    }
}

// ============================ launch ================================================

extern "C" void kernel_launch(void* const* d_in, const int* in_sizes, int n_in,
                              void* d_out, int out_size, void* d_ws, size_t ws_size,
                              hipStream_t stream) {
    const float* x    = (const float*)d_in[0];
    const float* wgt  = (const float*)d_in[1];
    const float* bias = (const float*)d_in[2];
    float* out = (float*)d_out;

    const size_t wsB_bytes = (size_t)OO * KTOT;                 // 589,824
    const size_t xs_bytes  = (size_t)NB * PH * PW * 256;        // 27,557,888
    if (ws_size >= wsB_bytes + xs_bytes) {
        int8_t* wsB = (int8_t*)d_ws;
        int8_t* xs  = (int8_t*)d_ws + wsB_bytes;
        pack_xs_kernel<<<dim3(PH, NB), 256, 0, stream>>>(x, xs);
        pack_wsB_kernel<<<dim3(OO), 256, 0, stream>>>(wgt, wsB);
        const int n_blocks = NB * SS / 128;                     // 784 (BN = whole N)
        bconv_mfma_kernel<<<dim3(n_blocks), 256, 0, stream>>>(xs, wsB, bias, out);
    } else {
        // fallback: proven popcount path (R4)
        size_t px_bytes = (size_t)NB * CWN * SPAD * 8;
        size_t pw_off   = px_bytes;
        size_t pw_bytes = (size_t)OO * 9 * CWN * 8;
        size_t k_off    = pw_off + pw_bytes;
        uint64_t* px  = (uint64_t*)d_ws;
        uint64_t* pwb = (uint64_t*)((char*)d_ws + pw_off);
        int*      kt  = (int*)((char*)d_ws + k_off);
        dim3 gpx((SPAD + 255) / 256, CWN, NB);
        pack_x_kernel<<<gpx, 256, 0, stream>>>(x, px);
        int nwords = OO * 9 * CWN;
        pack_w_kernel<<<dim3((nwords + 3) / 4), 256, 0, stream>>>(wgt, pwb);
        build_k_kernel<<<dim3(1), 256, 0, stream>>>(pwb, kt);
        dim3 gcv(NB * SS / 256, OO / 32, 1);
        bconv_kernel<<<gcv, 256, 0, stream>>>(px, pwb, kt, bias, out);
    }
}